// Round 3
// baseline (484.031 us; speedup 1.0000x reference)
//
#include <hip/hip_runtime.h>
#include <hip/hip_cooperative_groups.h>
#include <hip/hip_bf16.h>
#include <hip/hip_fp16.h>

// Problem constants: B=2, N=10000, M=320000, QD=KD=HD=256, NUM_HEADS=8, dh=32.
#define DHID 256
#define NHEAD 8
#define BATCH 2
#define SORT_BLOCKS 512

namespace cg = cooperative_groups;

typedef _Float16 h8 __attribute__((ext_vector_type(8)));
typedef _Float16 h2 __attribute__((ext_vector_type(2)));
typedef float f4 __attribute__((ext_vector_type(4)));

// ---- fused sort: zero + hist + scan + scatter, ONE cooperative dispatch ----
// Replaces memset+hist+scan+scatter (4 dispatches, ~40us serial) with one
// ~15us kernel. 512 blocks x 256 thr: trivially co-resident (0 LDS, low VGPR).
__global__ __launch_bounds__(256) void sort_kernel(
    const int* __restrict__ mask, int* __restrict__ cnt, int* __restrict__ cur,
    int* __restrict__ ps, int* __restrict__ sdst, int* __restrict__ seid,
    int M, int N)
{
    cg::grid_group grid = cg::this_grid();
    const int t = threadIdx.x;
    const int gid = blockIdx.x * 256 + t;
    const int nth = gridDim.x * 256;

    // P0: zero bins
    for (int i = gid; i < N; i += nth) cnt[i] = 0;
    grid.sync();
    // P1: histogram of src
    for (int e = gid; e < M; e += nth) atomicAdd(&cnt[mask[e]], 1);
    grid.sync();
    // P2a: per-chunk partial sums (CH bins/chunk)
    const int CH = 16;
    const int NC = (N + CH - 1) / CH;          // 625 for N=10000
    if (gid < NC) {
        int s = 0;
        const int base = gid * CH;
#pragma unroll
        for (int i = 0; i < CH; ++i) { int j = base + i; if (j < N) s += cnt[j]; }
        ps[gid] = s;
    }
    grid.sync();
    // P2b: block 0 turns ps into exclusive chunk offsets
    if (blockIdx.x == 0) {
        __shared__ int ls[256];
        const int per = (NC + 255) / 256;      // 3
        const int base = t * per;
        int s = 0;
        for (int i = 0; i < per; ++i) { int j = base + i; if (j < NC) s += ps[j]; }
        ls[t] = s; __syncthreads();
        for (int off = 1; off < 256; off <<= 1) {
            int v = (t >= off) ? ls[t - off] : 0;
            __syncthreads(); ls[t] += v; __syncthreads();
        }
        int run = (t == 0) ? 0 : ls[t - 1];
        for (int i = 0; i < per; ++i) {
            int j = base + i;
            if (j < NC) { int v = ps[j]; ps[j] = run; run += v; }
        }
    }
    grid.sync();
    // P2c: exclusive bin offsets -> cur
    if (gid < NC) {
        int run = ps[gid];
        const int base = gid * CH;
#pragma unroll
        for (int i = 0; i < CH; ++i) {
            int j = base + i;
            if (j < N) { int v = cnt[j]; cur[j] = run; run += v; }
        }
    }
    grid.sync();
    // P3: counting-sort scatter. After this cur[s] = group END (start=end-cnt).
    for (int e = gid; e < M; e += nth) {
        int s = mask[e];
        int pos = atomicAdd(&cur[s], 1);
        sdst[pos] = mask[M + e];
        seid[pos] = e;
    }
}

// ---- prep: W transpose -> fp16, FRAG-ORDERED layout ----------------------
// Element (n,k) of W^T lands at half-index ((n>>4)*32 + (k>>3))*16*8 +
// (n&15)*8 + (k&7): a (ct,kc,quad) wave-load in the gemm reads 1KB
// contiguous. Stores are scattered 2B but total is only 128KB x2.
__global__ __launch_bounds__(256) void prep_kernel(
    const float* __restrict__ Wq, const float* __restrict__ Wk,
    _Float16* __restrict__ Wfq, _Float16* __restrict__ Wfk)
{
    const float* W = blockIdx.z ? Wk : Wq;
    _Float16* Wf   = blockIdx.z ? Wfk : Wfq;
    __shared__ float tile[32][33];
    const int tx = threadIdx.x;   // 0..31
    const int ty = threadIdx.y;   // 0..7
    const int n0 = blockIdx.x * 32;
    const int k0 = blockIdx.y * 32;
#pragma unroll
    for (int j = 0; j < 32; j += 8)
        tile[ty + j][tx] = W[(size_t)(k0 + ty + j) * DHID + n0 + tx];
    __syncthreads();
#pragma unroll
    for (int j = 0; j < 32; j += 8) {
        const int n = n0 + ty + j;
        const int k = k0 + tx;
        const size_t u = ((size_t)(n >> 4) * 32 + (k >> 3)) * 16 + (n & 15);
        Wf[u * 8 + (k & 7)] = (_Float16)tile[tx][ty + j];
    }
}

// ---- MFMA GEMM, ZERO-LDS streaming form ----------------------------------
// Old form: 64KB LDS -> 2 blocks/CU, 8 barriers -> HBM-latency-bound staging
// (~90us inferred). New: A-frags straight from global X (each 128B line
// consumed by one wave's 4 quads -> L1 merges; X read exactly once), B-frags
// from frag-ordered Wf (1KB contiguous per wave-load, L2-hot 128KB). No LDS,
// no barriers, 4 blocks/CU -> 4x the in-flight loads.
__global__ __launch_bounds__(256, 4) void gemm_mfma(
    const float* __restrict__ Xq, const float* __restrict__ Xk,
    const _Float16* __restrict__ Wfq, const _Float16* __restrict__ Wfk,
    _Float16* __restrict__ Qh, _Float16* __restrict__ Kh, int Mrows)
{
    const int t = threadIdx.x;
    const float* X     = blockIdx.z ? Xk : Xq;
    const _Float16* Wf = blockIdx.z ? Wfk : Wfq;
    _Float16* C        = blockIdx.z ? Kh : Qh;

    const int lane = t & 63;
    const int wave = t >> 6;
    const int quad = lane >> 4;
    const int l16  = lane & 15;
    const int rowBase = blockIdx.x * 64;
    int arow = rowBase + wave * 16 + l16;
    if (arow >= Mrows) arow = Mrows - 1;   // clamp: OOB tile-rows never stored

    // A-frags for all 8 k-chunks of this lane's row (same layout the old
    // LDS path produced: afrag = A[row=ar][k=(kc*4+quad)*8 .. +7]).
    h8 af[8];
#pragma unroll
    for (int kc = 0; kc < 8; ++kc) {
        const float* p = X + (size_t)arow * DHID + (kc * 4 + quad) * 8;
        f4 v0 = *(const f4*)p;
        f4 v1 = *(const f4*)(p + 4);
        h8 hv;
        hv[0]=(_Float16)v0[0]; hv[1]=(_Float16)v0[1]; hv[2]=(_Float16)v0[2]; hv[3]=(_Float16)v0[3];
        hv[4]=(_Float16)v1[0]; hv[5]=(_Float16)v1[1]; hv[6]=(_Float16)v1[2]; hv[7]=(_Float16)v1[3];
        af[kc] = hv;
    }

#pragma unroll 1
    for (int ct64 = 0; ct64 < 4; ++ct64) {
        f4 acc[4] = {{0,0,0,0},{0,0,0,0},{0,0,0,0},{0,0,0,0}};
#pragma unroll
        for (int kc = 0; kc < 8; ++kc) {
#pragma unroll
            for (int ct = 0; ct < 4; ++ct) {
                // bfrag = Wt[n=ct64*64+ct*16+l16][(kc*4+quad)*8 .. +7]
                const h8 bf = *(const h8*)(Wf +
                    (((size_t)(ct64 * 4 + ct) * 32 + kc * 4 + quad) * 16 + l16) * 8);
                acc[ct] = __builtin_amdgcn_mfma_f32_16x16x32_f16(af[kc], bf, acc[ct], 0, 0, 0);
            }
        }
#pragma unroll
        for (int ct = 0; ct < 4; ++ct) {
#pragma unroll
            for (int r = 0; r < 4; ++r) {
                int grow = rowBase + wave * 16 + quad * 4 + r;
                if (grow < Mrows)
                    C[(size_t)grow * DHID + ct64 * 64 + ct * 16 + l16] = (_Float16)acc[ct][r];
            }
        }
    }
}

// ---- Edge kernel: one wave per src group, BOTH batches -------------------
// r2 was latency-bound (5.5 TB/s delivered vs 10.2 achievable): only 4
// outstanding K loads/iter. Fusing both batches doubles in-flight loads to 8,
// halves index traffic, and replaces lane<8-load+shfl with direct L1
// broadcast loads. Register seg-sums, no atomics; pass 2 re-reads own ehs
// (same CU, L2-hot), normalizes, scatters to out at original edge id.
__global__ __launch_bounds__(256, 6) void edge_kernel(
    const _Float16* __restrict__ Qh, const _Float16* __restrict__ Kh,
    const int* __restrict__ cnt, const int* __restrict__ cur,
    const int* __restrict__ sdst, const int* __restrict__ seid,
    _Float16* __restrict__ ehs, float* __restrict__ out, int M, int N)
{
    const int lane = threadIdx.x & 63;
    const int wave = threadIdx.x >> 6;
    const int c    = lane & 31;     // 16B chunk within row (c*8 halves)
    const int half = lane >> 5;     // which edge of the pair
    const int h    = c >> 2;        // head of this chunk
    const int src  = blockIdx.x * 4 + wave;
    if (src >= N) return;
    const int deg = cnt[src];
    if (deg == 0) return;
    const int end   = cur[src];         // post-scatter cursor = group end
    const int start = end - deg;

    const _Float16* Q0 = Qh;
    const _Float16* Q1 = Qh + (size_t)N * DHID;
    const _Float16* K0 = Kh;
    const _Float16* K1 = Kh + (size_t)N * DHID;

    // Q rows (both batches) resident in registers for the whole group
    const h8 q0 = *(const h8*)(Q0 + (size_t)src * DHID + c * 8);
    const h8 q1 = *(const h8*)(Q1 + (size_t)src * DHID + c * 8);

    float seg0 = 0.f, seg1 = 0.f;       // valid on lanes with (c&3)==0
    for (int it = start; it < end; it += 8) {
        int pos[4], dd[4];
#pragma unroll
        for (int p = 0; p < 4; ++p) {
            pos[p] = it + p * 2 + half;
            int ec = pos[p] < end ? pos[p] : end - 1;
            dd[p] = sdst[ec];           // 32B line broadcast across lanes
        }
        h8 k0v[4], k1v[4];
#pragma unroll
        for (int p = 0; p < 4; ++p) {
            k0v[p] = *(const h8*)(K0 + (size_t)dd[p] * DHID + c * 8);
            k1v[p] = *(const h8*)(K1 + (size_t)dd[p] * DHID + c * 8);
        }
#pragma unroll
        for (int p = 0; p < 4; ++p) {
            float s0 = 0.f, s1 = 0.f;
#if __has_builtin(__builtin_amdgcn_fdot2)
#pragma unroll
            for (int u = 0; u < 4; ++u) {
                h2 a0, b0, a1, b1;
                a0[0] = q0[2*u];      a0[1] = q0[2*u+1];
                b0[0] = k0v[p][2*u];  b0[1] = k0v[p][2*u+1];
                a1[0] = q1[2*u];      a1[1] = q1[2*u+1];
                b1[0] = k1v[p][2*u];  b1[1] = k1v[p][2*u+1];
                s0 = __builtin_amdgcn_fdot2(a0, b0, s0, false);
                s1 = __builtin_amdgcn_fdot2(a1, b1, s1, false);
            }
#else
#pragma unroll
            for (int u = 0; u < 8; ++u) {
                s0 += (float)q0[u] * (float)k0v[p][u];
                s1 += (float)q1[u] * (float)k1v[p][u];
            }
#endif
            s0 += __shfl_xor(s0, 1); s0 += __shfl_xor(s0, 2);
            s1 += __shfl_xor(s1, 1); s1 += __shfl_xor(s1, 2);
            if ((c & 3) == 0 && pos[p] < end) {
                _Float16 e0 = (_Float16)expf(s0 * 0.0625f);   // 1/sqrt(256)
                _Float16 e1 = (_Float16)expf(s1 * 0.0625f);
                ehs[(size_t)pos[p] * NHEAD + h] = e0;                        // b=0
                ehs[(size_t)M * NHEAD + (size_t)pos[p] * NHEAD + h] = e1;    // b=1
                seg0 += (float)e0; seg1 += (float)e1;
            }
        }
    }

    // combine the two halves' partials; all lanes get the group totals
    seg0 += __shfl_xor(seg0, 32);
    seg1 += __shfl_xor(seg1, 32);
    const float r0 = __builtin_amdgcn_rcpf(seg0 + 1e-16f);
    const float r1 = __builtin_amdgcn_rcpf(seg1 + 1e-16f);

    // pass 2: same-CU re-read of own ev, normalize, scatter at original id
    for (int it = start; it < end; it += 8) {
#pragma unroll
        for (int p = 0; p < 4; ++p) {
            int pos = it + p * 2 + half;
            if ((c & 3) == 0 && pos < end) {
                int eid = seid[pos];
                float v0 = (float)ehs[(size_t)pos * NHEAD + h];
                float v1 = (float)ehs[(size_t)M * NHEAD + (size_t)pos * NHEAD + h];
                __builtin_nontemporal_store(v0 * r0, &out[(size_t)eid * NHEAD + h]);
                __builtin_nontemporal_store(v1 * r1,
                    &out[(size_t)M * NHEAD + (size_t)eid * NHEAD + h]);
            }
        }
    }
}

extern "C" void kernel_launch(void* const* d_in, const int* in_sizes, int n_in,
                              void* d_out, int out_size, void* d_ws, size_t ws_size,
                              hipStream_t stream) {
    const float* x_q  = (const float*)d_in[0];
    const float* x_k  = (const float*)d_in[1];
    const int*   mask = (const int*)d_in[2];
    const float* w_q  = (const float*)d_in[3];
    const float* w_k  = (const float*)d_in[4];
    float* out = (float*)d_out;

    const int M = in_sizes[2] / 2;                 // 320000
    const int N = in_sizes[0] / (BATCH * DHID);    // 10000
    const int Mrows = BATCH * N;                   // 20000

    _Float16* Qh  = (_Float16*)d_ws;
    _Float16* Kh  = Qh  + (size_t)Mrows * DHID;
    _Float16* Wfq = Kh  + (size_t)Mrows * DHID;
    _Float16* Wfk = Wfq + (size_t)DHID * DHID;
    _Float16* ehs = Wfk + (size_t)DHID * DHID;     // [B][M][NHEAD] fp16, sorted order
    int*      cnt = (int*)(ehs + (size_t)BATCH * M * NHEAD);
    int*      cur  = cnt + N;
    int*      ps   = cur + N;
    int*      sdst = ps + 1024;
    int*      seid = sdst + M;

    // fused sort: one cooperative dispatch
    {
        void* args[] = { (void*)&mask, (void*)&cnt, (void*)&cur, (void*)&ps,
                         (void*)&sdst, (void*)&seid, (void*)&M, (void*)&N };
        hipLaunchCooperativeKernel((void*)sort_kernel, dim3(SORT_BLOCKS), dim3(256),
                                   args, 0, stream);
    }

    // W transpose -> frag-ordered fp16
    prep_kernel<<<dim3(DHID / 32, DHID / 32, 2), dim3(32, 8), 0, stream>>>(
        w_q, w_k, Wfq, Wfk);

    // GEMM: zero-LDS streaming, 313 blocks x 2
    const int nx = (Mrows + 63) / 64;              // 313
    gemm_mfma<<<dim3(nx, 1, 2), 256, 0, stream>>>(
        x_q, x_k, Wfq, Wfk, Qh, Kh, Mrows);

    // edge: one wave per src group, both batches; fused normalize + scatter
    edge_kernel<<<dim3((N + 3) / 4), 256, 0, stream>>>(
        Qh, Kh, cnt, cur, sdst, seid, ehs, out, M, N);
}

// Round 4
// 218.391 us; speedup vs baseline: 2.2163x; 2.2163x over previous
//
#include <hip/hip_runtime.h>
#include <hip/hip_bf16.h>
#include <hip/hip_fp16.h>

// Problem constants: B=2, N=10000, M=320000, QD=KD=HD=256, NUM_HEADS=8, dh=32.
#define DHID 256
#define NHEAD 8
#define BATCH 2

typedef _Float16 h8 __attribute__((ext_vector_type(8)));
typedef _Float16 h2 __attribute__((ext_vector_type(2)));
typedef float f4 __attribute__((ext_vector_type(4)));
typedef int i2 __attribute__((ext_vector_type(2)));

// ---- prep: W transpose -> fp16 frag-ordered (z<2) + src histogram (z==2) --
// Element (n,k) of W^T lands at half-index ((n>>4)*32+(k>>3))*16*8 +
// (n&15)*8 + (k&7): a (ct,kc,quad) wave-load in the gemm reads 1KB
// contiguous. Hist rides on z==2 (64 blocks) -- r1-proven free.
__global__ __launch_bounds__(256) void prep_kernel(
    const float* __restrict__ Wq, const float* __restrict__ Wk,
    _Float16* __restrict__ Wfq, _Float16* __restrict__ Wfk,
    const int* __restrict__ mask, int* __restrict__ cnt, int M)
{
    if (blockIdx.z == 2) {          // histogram of mask[0] (src) over N bins
        const int tid = threadIdx.y * 32 + threadIdx.x;
        const int bid = blockIdx.y * 8 + blockIdx.x;     // 0..63
        for (int e = bid * 256 + tid; e < M; e += 64 * 256)
            atomicAdd(&cnt[mask[e]], 1);
        return;
    }
    const float* W = blockIdx.z ? Wk : Wq;
    _Float16* Wf   = blockIdx.z ? Wfk : Wfq;
    __shared__ float tile[32][33];
    const int tx = threadIdx.x;   // 0..31
    const int ty = threadIdx.y;   // 0..7
    const int n0 = blockIdx.x * 32;
    const int k0 = blockIdx.y * 32;
#pragma unroll
    for (int j = 0; j < 32; j += 8)
        tile[ty + j][tx] = W[(size_t)(k0 + ty + j) * DHID + n0 + tx];
    __syncthreads();
#pragma unroll
    for (int j = 0; j < 32; j += 8) {
        const int n = n0 + ty + j;
        const int k = k0 + tx;
        const size_t u = ((size_t)(n >> 4) * 32 + (k >> 3)) * 16 + (n & 15);
        Wf[u * 8 + (k & 7)] = (_Float16)tile[tx][ty + j];
    }
}

// ---- scan: exclusive prefix sum cnt -> cur (1 block, ~6us) ----------------
__global__ __launch_bounds__(1024) void scan_kernel(
    const int* __restrict__ cnt, int* __restrict__ cur, int N)
{
    __shared__ int sums[1024];
    const int t = threadIdx.x;
    const int per = (N + 1023) >> 10;
    const int base = t * per;
    int s = 0;
    for (int i = 0; i < per; ++i) {
        int j = base + i;
        if (j < N) s += cnt[j];
    }
    sums[t] = s;
    __syncthreads();
    for (int off = 1; off < 1024; off <<= 1) {      // Hillis-Steele inclusive
        int v = (t >= off) ? sums[t - off] : 0;
        __syncthreads();
        sums[t] += v;
        __syncthreads();
    }
    int run = (t == 0) ? 0 : sums[t - 1];
    for (int i = 0; i < per; ++i) {
        int j = base + i;
        if (j < N) { cur[j] = run; run += cnt[j]; }
    }
}

// ---- scatter: counting-sort edges by src, packed {dst,eid} 8B stores ------
// After this, cur[s] = group END offset (start = end - cnt[s]).
__global__ __launch_bounds__(256) void scatter_kernel(
    const int* __restrict__ mask, int* __restrict__ cur,
    int* __restrict__ sde, int M)
{
    int e = blockIdx.x * 256 + threadIdx.x;
    if (e >= M) return;
    int s = mask[e];
    int pos = atomicAdd(&cur[s], 1);
    i2 v; v[0] = mask[M + e]; v[1] = e;
    *(i2*)(sde + (size_t)pos * 2) = v;
}

// ---- MFMA GEMM, ZERO-LDS streaming form ----------------------------------
// A-frags straight from global X (16 cache lines per wave-instruction, X read
// once), B-frags from frag-ordered Wf (1KB contiguous per wave-load, L1/L2-hot
// 128KB). No LDS, no barriers, 4 blocks/CU.
__global__ __launch_bounds__(256, 4) void gemm_mfma(
    const float* __restrict__ Xq, const float* __restrict__ Xk,
    const _Float16* __restrict__ Wfq, const _Float16* __restrict__ Wfk,
    _Float16* __restrict__ Qh, _Float16* __restrict__ Kh, int Mrows)
{
    const int t = threadIdx.x;
    const float* X     = blockIdx.z ? Xk : Xq;
    const _Float16* Wf = blockIdx.z ? Wfk : Wfq;
    _Float16* C        = blockIdx.z ? Kh : Qh;

    const int lane = t & 63;
    const int wave = t >> 6;
    const int quad = lane >> 4;
    const int l16  = lane & 15;
    const int rowBase = blockIdx.x * 64;
    int arow = rowBase + wave * 16 + l16;
    if (arow >= Mrows) arow = Mrows - 1;   // clamp: OOB tile-rows never stored

    // A-frags for all 8 k-chunks of this lane's row
    h8 af[8];
#pragma unroll
    for (int kc = 0; kc < 8; ++kc) {
        const float* p = X + (size_t)arow * DHID + (kc * 4 + quad) * 8;
        f4 v0 = *(const f4*)p;
        f4 v1 = *(const f4*)(p + 4);
        h8 hv;
        hv[0]=(_Float16)v0[0]; hv[1]=(_Float16)v0[1]; hv[2]=(_Float16)v0[2]; hv[3]=(_Float16)v0[3];
        hv[4]=(_Float16)v1[0]; hv[5]=(_Float16)v1[1]; hv[6]=(_Float16)v1[2]; hv[7]=(_Float16)v1[3];
        af[kc] = hv;
    }

#pragma unroll 1
    for (int ct64 = 0; ct64 < 4; ++ct64) {
        f4 acc[4] = {{0,0,0,0},{0,0,0,0},{0,0,0,0},{0,0,0,0}};
#pragma unroll
        for (int kc = 0; kc < 8; ++kc) {
#pragma unroll
            for (int ct = 0; ct < 4; ++ct) {
                // bfrag = Wt[n=ct64*64+ct*16+l16][(kc*4+quad)*8 .. +7]
                const h8 bf = *(const h8*)(Wf +
                    (((size_t)(ct64 * 4 + ct) * 32 + kc * 4 + quad) * 16 + l16) * 8);
                acc[ct] = __builtin_amdgcn_mfma_f32_16x16x32_f16(af[kc], bf, acc[ct], 0, 0, 0);
            }
        }
#pragma unroll
        for (int ct = 0; ct < 4; ++ct) {
#pragma unroll
            for (int r = 0; r < 4; ++r) {
                int grow = rowBase + wave * 16 + quad * 4 + r;
                if (grow < Mrows)
                    C[(size_t)grow * DHID + ct64 * 64 + ct * 16 + l16] = (_Float16)acc[ct][r];
            }
        }
    }
}

// ---- Edge kernel: one wave per src group, BOTH batches -------------------
// Q rows (both batches) register-resident per group; 8 outstanding K-loads
// per iteration; register seg-sums (no atomics); pass 2 re-reads own ehs
// (L2-hot), normalizes, scatters to out at original edge id.
__global__ __launch_bounds__(256, 6) void edge_kernel(
    const _Float16* __restrict__ Qh, const _Float16* __restrict__ Kh,
    const int* __restrict__ cnt, const int* __restrict__ cur,
    const int* __restrict__ sde, _Float16* __restrict__ ehs,
    float* __restrict__ out, int M, int N)
{
    const int lane = threadIdx.x & 63;
    const int wave = threadIdx.x >> 6;
    const int c    = lane & 31;     // 16B chunk within row (c*8 halves)
    const int half = lane >> 5;     // which edge of the pair
    const int h    = c >> 2;        // head of this chunk
    const int src  = blockIdx.x * 4 + wave;
    if (src >= N) return;
    const int deg = cnt[src];
    if (deg == 0) return;
    const int end   = cur[src];         // post-scatter cursor = group end
    const int start = end - deg;

    const _Float16* Q0 = Qh;
    const _Float16* Q1 = Qh + (size_t)N * DHID;
    const _Float16* K0 = Kh;
    const _Float16* K1 = Kh + (size_t)N * DHID;

    // Q rows (both batches) resident in registers for the whole group
    const h8 q0 = *(const h8*)(Q0 + (size_t)src * DHID + c * 8);
    const h8 q1 = *(const h8*)(Q1 + (size_t)src * DHID + c * 8);

    float seg0 = 0.f, seg1 = 0.f;       // valid on lanes with (c&3)==0
    for (int it = start; it < end; it += 8) {
        int pos[4], dd[4];
#pragma unroll
        for (int p = 0; p < 4; ++p) {
            pos[p] = it + p * 2 + half;
            int ec = pos[p] < end ? pos[p] : end - 1;
            dd[p] = sde[(size_t)ec * 2];        // packed .x = dst (broadcast)
        }
        h8 k0v[4], k1v[4];
#pragma unroll
        for (int p = 0; p < 4; ++p) {
            k0v[p] = *(const h8*)(K0 + (size_t)dd[p] * DHID + c * 8);
            k1v[p] = *(const h8*)(K1 + (size_t)dd[p] * DHID + c * 8);
        }
#pragma unroll
        for (int p = 0; p < 4; ++p) {
            float s0 = 0.f, s1 = 0.f;
#if __has_builtin(__builtin_amdgcn_fdot2)
#pragma unroll
            for (int u = 0; u < 4; ++u) {
                h2 a0, b0, a1, b1;
                a0[0] = q0[2*u];      a0[1] = q0[2*u+1];
                b0[0] = k0v[p][2*u];  b0[1] = k0v[p][2*u+1];
                a1[0] = q1[2*u];      a1[1] = q1[2*u+1];
                b1[0] = k1v[p][2*u];  b1[1] = k1v[p][2*u+1];
                s0 = __builtin_amdgcn_fdot2(a0, b0, s0, false);
                s1 = __builtin_amdgcn_fdot2(a1, b1, s1, false);
            }
#else
#pragma unroll
            for (int u = 0; u < 8; ++u) {
                s0 += (float)q0[u] * (float)k0v[p][u];
                s1 += (float)q1[u] * (float)k1v[p][u];
            }
#endif
            s0 += __shfl_xor(s0, 1); s0 += __shfl_xor(s0, 2);
            s1 += __shfl_xor(s1, 1); s1 += __shfl_xor(s1, 2);
            if ((c & 3) == 0 && pos[p] < end) {
                _Float16 e0 = (_Float16)expf(s0 * 0.0625f);   // 1/sqrt(256)
                _Float16 e1 = (_Float16)expf(s1 * 0.0625f);
                ehs[(size_t)pos[p] * NHEAD + h] = e0;                        // b=0
                ehs[(size_t)M * NHEAD + (size_t)pos[p] * NHEAD + h] = e1;    // b=1
                seg0 += (float)e0; seg1 += (float)e1;
            }
        }
    }

    // combine the two halves' partials; all lanes get the group totals
    seg0 += __shfl_xor(seg0, 32);
    seg1 += __shfl_xor(seg1, 32);
    const float r0 = __builtin_amdgcn_rcpf(seg0 + 1e-16f);
    const float r1 = __builtin_amdgcn_rcpf(seg1 + 1e-16f);

    // pass 2: same-CU re-read of own ev, normalize, scatter at original id
    for (int it = start; it < end; it += 8) {
#pragma unroll
        for (int p = 0; p < 4; ++p) {
            int pos = it + p * 2 + half;
            if ((c & 3) == 0 && pos < end) {
                int eid = sde[(size_t)pos * 2 + 1];   // packed .y = orig edge id
                float v0 = (float)ehs[(size_t)pos * NHEAD + h];
                float v1 = (float)ehs[(size_t)M * NHEAD + (size_t)pos * NHEAD + h];
                __builtin_nontemporal_store(v0 * r0, &out[(size_t)eid * NHEAD + h]);
                __builtin_nontemporal_store(v1 * r1,
                    &out[(size_t)M * NHEAD + (size_t)eid * NHEAD + h]);
            }
        }
    }
}

extern "C" void kernel_launch(void* const* d_in, const int* in_sizes, int n_in,
                              void* d_out, int out_size, void* d_ws, size_t ws_size,
                              hipStream_t stream) {
    const float* x_q  = (const float*)d_in[0];
    const float* x_k  = (const float*)d_in[1];
    const int*   mask = (const int*)d_in[2];
    const float* w_q  = (const float*)d_in[3];
    const float* w_k  = (const float*)d_in[4];
    float* out = (float*)d_out;

    const int M = in_sizes[2] / 2;                 // 320000
    const int N = in_sizes[0] / (BATCH * DHID);    // 10000
    const int Mrows = BATCH * N;                   // 20000

    _Float16* Qh  = (_Float16*)d_ws;
    _Float16* Kh  = Qh  + (size_t)Mrows * DHID;
    _Float16* Wfq = Kh  + (size_t)Mrows * DHID;
    _Float16* Wfk = Wfq + (size_t)DHID * DHID;
    _Float16* ehs = Wfk + (size_t)DHID * DHID;     // [B][M][NHEAD] fp16, sorted order
    int*      cnt = (int*)(ehs + (size_t)BATCH * M * NHEAD);
    int*      cur = cnt + N;
    int*      sde = cur + N;                       // packed {dst, eid} pairs

    // sort chain: cnt=0 -> (prep + hist) -> scan -> scatter (all flat)
    hipMemsetAsync(cnt, 0, (size_t)N * sizeof(int), stream);
    prep_kernel<<<dim3(DHID / 32, DHID / 32, 3), dim3(32, 8), 0, stream>>>(
        w_q, w_k, Wfq, Wfk, mask, cnt, M);
    scan_kernel<<<1, 1024, 0, stream>>>(cnt, cur, N);
    scatter_kernel<<<(M + 255) / 256, 256, 0, stream>>>(mask, cur, sde, M);

    // GEMM: zero-LDS streaming, 313 blocks x 2
    const int nx = (Mrows + 63) / 64;              // 313
    gemm_mfma<<<dim3(nx, 1, 2), 256, 0, stream>>>(
        x_q, x_k, Wfq, Wfk, Qh, Kh, Mrows);

    // edge: one wave per src group, both batches; fused normalize + scatter
    edge_kernel<<<dim3((N + 3) / 4), 256, 0, stream>>>(
        Qh, Kh, cnt, cur, sde, ehs, out, M, N);
}